// Round 1
// baseline (970.623 us; speedup 1.0000x reference)
//
#include <hip/hip_runtime.h>
#include <stdint.h>

typedef __attribute__((ext_vector_type(8))) short short8;
typedef __attribute__((ext_vector_type(8))) unsigned short ushort8;
typedef __attribute__((ext_vector_type(4))) float float4_t;

#define AS1 __attribute__((address_space(1)))
#define AS3 __attribute__((address_space(3)))

// round-to-nearest-even fp32 -> bf16 (branch-free)
__device__ __forceinline__ unsigned short f2bf(float f) {
    union { float f; unsigned u; } c; c.f = f;
    return (unsigned short)((c.u + 0x7fffu + ((c.u >> 16) & 1u)) >> 16);
}

// async global->LDS, 16B per lane. LDS dest must be wave-uniform base + lane*16.
// addrspace conversion via uintptr_t: generic LDS ptr low 32 bits == LDS offset.
__device__ __forceinline__ void load16_lds(const void* g, void* l) {
    __builtin_amdgcn_global_load_lds((const AS1 void*)(uintptr_t)g,
                                     (AS3 void*)(uintptr_t)l, 16, 0, 0);
}

// ---------------------------------------------------------------------------
// fp32 -> bf16 convert, 8 elems/thread
__global__ __launch_bounds__(256)
void cvt_x(const float4_t* __restrict__ x, unsigned short* __restrict__ xb, int n8) {
    int i = blockIdx.x * 256 + threadIdx.x;
    if (i >= n8) return;
    float4_t a = x[2 * i], b = x[2 * i + 1];
    ushort8 v;
    v[0] = f2bf(a[0]); v[1] = f2bf(a[1]); v[2] = f2bf(a[2]); v[3] = f2bf(a[3]);
    v[4] = f2bf(b[0]); v[5] = f2bf(b[1]); v[6] = f2bf(b[2]); v[7] = f2bf(b[3]);
    ((ushort8*)xb)[i] = v;
}

// ---------------------------------------------------------------------------
// small prep: weight transpose+convert (B^T layout N x K), dense bias (16,49,49)
__global__ __launch_bounds__(256)
void prep(const float* __restrict__ qkv_w, const float* __restrict__ proj_w,
          const float* __restrict__ bias_tab, const int* __restrict__ rel_idx,
          unsigned short* __restrict__ qkv_wT, unsigned short* __restrict__ proj_wT,
          float* __restrict__ biasD) {
    int i = blockIdx.x * 256 + threadIdx.x;
    if (i < 786432) {                       // qkv_wT[n][k], n<1536,k<512
        int n = i >> 9, k = i & 511;
        qkv_wT[i] = f2bf(qkv_w[k * 1536 + n]);
    } else if (i < 1048576) {               // proj_wT[n][k], n<512,k<512
        int j = i - 786432;
        int n = j >> 9, k = j & 511;
        proj_wT[j] = f2bf(proj_w[k * 512 + n]);
    } else if (i < 1086992) {               // biasD[h][m*49+n]
        int j = i - 1048576;
        int h = j / 2401, mn = j % 2401;
        biasD[j] = bias_tab[rel_idx[mn] * 16 + h];
    }
}

// ---------------------------------------------------------------------------
// m97-style bf16 GEMM: C(MxN) = A(MxK) * B^T  (B stored N x K row-major)
// 128x128 tile, BK=32, 4 waves (2x2 of 64x64), 16x16x32 bf16 MFMA.
// MODE 0: bf16 out, fp32 bias, cols<512 scaled by qscale (QKV epilogue)
// MODE 1: fp32 out + bias (proj epilogue)
template <int MODE>
__global__ __launch_bounds__(256)
void gemm_bt(const unsigned short* __restrict__ A, const unsigned short* __restrict__ B,
             void* __restrict__ Cv, const float* __restrict__ bias,
             int M, int N, int K, float qscale) {
    __shared__ __align__(16) unsigned short As[128 * 32];
    __shared__ __align__(16) unsigned short Bs[128 * 32];

    const int t = threadIdx.x;
    const int lane = t & 63;
    const int wave = t >> 6;
    const int col = lane & 15;
    const int quad = lane >> 4;
    const int wm = (wave & 1) * 64;
    const int wn = (wave >> 1) * 64;
    const int m0 = blockIdx.y * 128;
    const int n0 = blockIdx.x * 128;

    float4_t acc[4][4] = {};

    const int row = t >> 2;   // 0..63 (two issues cover 128 rows)
    const int seg = t & 3;    // 16B segment within a 64B row
    const unsigned short* Ag0 = A + (size_t)(m0 + row) * K + seg * 8;
    const unsigned short* Ag1 = A + (size_t)(m0 + 64 + row) * K + seg * 8;
    const unsigned short* Bg0 = B + (size_t)(n0 + row) * K + seg * 8;
    const unsigned short* Bg1 = B + (size_t)(n0 + 64 + row) * K + seg * 8;

    for (int kk = 0; kk < K; kk += 32) {
        __syncthreads();                       // protect LDS from prev-iter readers
        load16_lds(Ag0 + kk, &As[t * 8]);
        load16_lds(Ag1 + kk, &As[2048 + t * 8]);
        load16_lds(Bg0 + kk, &Bs[t * 8]);
        load16_lds(Bg1 + kk, &Bs[2048 + t * 8]);
        __syncthreads();                       // drain vmcnt + barrier

        short8 a[4], b[4];
#pragma unroll
        for (int i = 0; i < 4; ++i)
            a[i] = *(const short8*)&As[(wm + i * 16 + col) * 32 + quad * 8];
#pragma unroll
        for (int j = 0; j < 4; ++j)
            b[j] = *(const short8*)&Bs[(wn + j * 16 + col) * 32 + quad * 8];
#pragma unroll
        for (int i = 0; i < 4; ++i)
#pragma unroll
            for (int j = 0; j < 4; ++j)
                acc[i][j] = __builtin_amdgcn_mfma_f32_16x16x32_bf16(a[i], b[j], acc[i][j], 0, 0, 0);
    }

    // C/D layout: D[m=quad*4+r][n=lane&15] per 16x16 tile
    if (MODE == 0) {
        unsigned short* C = (unsigned short*)Cv;
#pragma unroll
        for (int j = 0; j < 4; ++j) {
            int gc = n0 + wn + j * 16 + col;
            float bv = bias[gc];
            float sc = (gc < 512) ? qscale : 1.0f;   // q section gets d^-0.5
#pragma unroll
            for (int i = 0; i < 4; ++i)
#pragma unroll
                for (int r = 0; r < 4; ++r) {
                    int gr = m0 + wm + i * 16 + quad * 4 + r;
                    C[(size_t)gr * N + gc] = f2bf((acc[i][j][r] + bv) * sc);
                }
        }
    } else {
        float* C = (float*)Cv;
#pragma unroll
        for (int j = 0; j < 4; ++j) {
            int gc = n0 + wn + j * 16 + col;
            float bv = bias[gc];
#pragma unroll
            for (int i = 0; i < 4; ++i)
#pragma unroll
                for (int r = 0; r < 4; ++r) {
                    int gr = m0 + wm + i * 16 + quad * 4 + r;
                    C[(size_t)gr * N + gc] = acc[i][j][r] + bv;
                }
        }
    }
}

// ---------------------------------------------------------------------------
// window attention: one wave per (window, head). 49 padded to 64.
// qkv layout: (100352, 1536) bf16, cols [0,512)=q (pre-scaled), [512,1024)=k, [1024,1536)=v
__global__ __launch_bounds__(64)
void attn_win(const unsigned short* __restrict__ qkv,
              const float* __restrict__ mask,     // (64,49,49) fp32
              const float* __restrict__ biasD,    // (16,49,49) fp32
              unsigned short* __restrict__ attn_out) {  // (100352,512) bf16
    __shared__ __align__(16) unsigned short P[64 * 64];   // probs, row-major
    __shared__ __align__(16) unsigned short Vt[32 * 64];  // V^T: [dd][token]

    const int bh = blockIdx.x;
    const int w = bh >> 4;
    const int hh = bh & 15;
    const int lane = threadIdx.x;
    const int col = lane & 15;
    const int quad = lane >> 4;
    const size_t rowbase = (size_t)(w * 49) * 1536;

    // ---- stage V^T (tokens >=49 zero) ----
    {
        ushort8 u0 = {}, u1 = {}, u2 = {}, u3 = {};
        if (lane < 49) {
            const ushort8* vp = (const ushort8*)(qkv + rowbase + (size_t)lane * 1536 + 1024 + hh * 32);
            u0 = vp[0]; u1 = vp[1]; u2 = vp[2]; u3 = vp[3];
        }
#pragma unroll
        for (int c = 0; c < 8; ++c) {
            Vt[(c) * 64 + lane] = u0[c];
            Vt[(c + 8) * 64 + lane] = u1[c];
            Vt[(c + 16) * 64 + lane] = u2[c];
            Vt[(c + 24) * 64 + lane] = u3[c];
        }
    }

    // ---- S = Q K^T via MFMA, fragments straight from global ----
    float4_t s[4][4] = {};
    {
        short8 qf[4], kf[4];
#pragma unroll
        for (int i = 0; i < 4; ++i) {
            int m = i * 16 + col; if (m > 48) m = 48;   // clamp: rows >=49 discarded later
            qf[i] = *(const short8*)(qkv + rowbase + (size_t)m * 1536 + hh * 32 + quad * 8);
            int n = i * 16 + col; if (n > 48) n = 48;
            kf[i] = *(const short8*)(qkv + rowbase + (size_t)n * 1536 + 512 + hh * 32 + quad * 8);
        }
#pragma unroll
        for (int i = 0; i < 4; ++i)
#pragma unroll
            for (int j = 0; j < 4; ++j)
                s[i][j] = __builtin_amdgcn_mfma_f32_16x16x32_bf16(qf[i], kf[j], s[i][j], 0, 0, 0);
    }

    // ---- + rel-pos bias + shift mask; kill cols >= 49 ----
    const float* mk = mask + (size_t)(w & 63) * 2401;
    const float* bs = biasD + (size_t)hh * 2401;
#pragma unroll
    for (int j = 0; j < 4; ++j) {
        int n = j * 16 + col;
#pragma unroll
        for (int i = 0; i < 4; ++i)
#pragma unroll
            for (int r = 0; r < 4; ++r) {
                int m = i * 16 + quad * 4 + r;
                float v = s[i][j][r];
                if (n < 49) { if (m < 49) v += mk[m * 49 + n] + bs[m * 49 + n]; }
                else v = -1e30f;
                s[i][j][r] = v;
            }
    }

    // ---- softmax per row (row lives in one 16-lane quad group, 4 vals/lane) ----
#pragma unroll
    for (int i = 0; i < 4; ++i)
#pragma unroll
        for (int r = 0; r < 4; ++r) {
            float mx = fmaxf(fmaxf(s[i][0][r], s[i][1][r]), fmaxf(s[i][2][r], s[i][3][r]));
#pragma unroll
            for (int off = 1; off < 16; off <<= 1)
                mx = fmaxf(mx, __shfl_xor(mx, off, 16));
            float e0 = __expf(s[i][0][r] - mx);
            float e1 = __expf(s[i][1][r] - mx);
            float e2 = __expf(s[i][2][r] - mx);
            float e3 = __expf(s[i][3][r] - mx);
            float sum = e0 + e1 + e2 + e3;
#pragma unroll
            for (int off = 1; off < 16; off <<= 1)
                sum += __shfl_xor(sum, off, 16);
            float inv = 1.0f / sum;
            s[i][0][r] = e0 * inv; s[i][1][r] = e1 * inv;
            s[i][2][r] = e2 * inv; s[i][3][r] = e3 * inv;
        }

    // ---- C-layout -> A-layout transform via LDS ----
#pragma unroll
    for (int i = 0; i < 4; ++i)
#pragma unroll
        for (int r = 0; r < 4; ++r) {
            int m = i * 16 + quad * 4 + r;
#pragma unroll
            for (int j = 0; j < 4; ++j)
                P[m * 64 + j * 16 + col] = f2bf(s[i][j][r]);
        }
    __syncthreads();

    // ---- O = P V ----
    float4_t o[4][2] = {};
#pragma unroll
    for (int s2 = 0; s2 < 2; ++s2) {
        short8 pa[4], vb[2];
#pragma unroll
        for (int i = 0; i < 4; ++i)
            pa[i] = *(const short8*)&P[(i * 16 + col) * 64 + s2 * 32 + quad * 8];
#pragma unroll
        for (int tj = 0; tj < 2; ++tj)
            vb[tj] = *(const short8*)&Vt[(tj * 16 + col) * 64 + s2 * 32 + quad * 8];
#pragma unroll
        for (int i = 0; i < 4; ++i)
#pragma unroll
            for (int tj = 0; tj < 2; ++tj)
                o[i][tj] = __builtin_amdgcn_mfma_f32_16x16x32_bf16(pa[i], vb[tj], o[i][tj], 0, 0, 0);
    }

    // ---- store (bf16, (M,512) row-major feeds proj GEMM) ----
#pragma unroll
    for (int i = 0; i < 4; ++i)
#pragma unroll
        for (int r = 0; r < 4; ++r) {
            int m = i * 16 + quad * 4 + r;
            if (m < 49) {
                size_t ob = (size_t)(w * 49 + m) * 512 + hh * 32;
                attn_out[ob + col] = f2bf(o[i][0][r]);
                attn_out[ob + 16 + col] = f2bf(o[i][1][r]);
            }
        }
}

// ---------------------------------------------------------------------------
extern "C" void kernel_launch(void* const* d_in, const int* in_sizes, int n_in,
                              void* d_out, int out_size, void* d_ws, size_t ws_size,
                              hipStream_t stream) {
    const float* x        = (const float*)d_in[0];
    const float* mask     = (const float*)d_in[1];
    const float* qkv_w    = (const float*)d_in[2];
    const float* qkv_b    = (const float*)d_in[3];
    const float* proj_w   = (const float*)d_in[4];
    const float* proj_b   = (const float*)d_in[5];
    const float* bias_tab = (const float*)d_in[6];
    const int*   rel_idx  = (const int*)d_in[7];
    float* out = (float*)d_out;

    char* ws = (char*)d_ws;
    size_t off = 0;
    auto carve = [&](size_t bytes) -> char* {
        char* p = ws + off;
        off += (bytes + 255) & ~(size_t)255;
        return p;
    };
    unsigned short* x_bf    = (unsigned short*)carve((size_t)51380224 * 2);   // 102.8 MB
    unsigned short* qkv_wT  = (unsigned short*)carve((size_t)786432 * 2);
    unsigned short* proj_wT = (unsigned short*)carve((size_t)262144 * 2);
    float*          biasD   = (float*)carve((size_t)38416 * 4);
    unsigned short* qkv_o   = (unsigned short*)carve((size_t)100352 * 1536 * 2); // 308.3 MB
    unsigned short* attn_o  = x_bf;  // x_bf dead after QKV GEMM; alias saves 103 MB

    cvt_x<<<25088, 256, 0, stream>>>((const float4_t*)x, x_bf, 6422528);
    prep<<<4247, 256, 0, stream>>>(qkv_w, proj_w, bias_tab, rel_idx, qkv_wT, proj_wT, biasD);
    // qkv = x @ qkv_w + b, q-cols scaled by 32^-0.5, bf16 out
    gemm_bt<0><<<dim3(12, 784), 256, 0, stream>>>(x_bf, qkv_wT, (void*)qkv_o, qkv_b,
                                                  100352, 1536, 512, 0.17677669529663687f);
    attn_win<<<32768, 64, 0, stream>>>(qkv_o, mask, biasD, attn_o);
    // out = attn_o @ proj_w + proj_b, fp32 out
    gemm_bt<1><<<dim3(4, 784), 256, 0, stream>>>(attn_o, proj_wT, (void*)out, proj_b,
                                                 100352, 512, 512, 1.0f);
}